// Round 1
// 409.869 us; speedup vs baseline: 1.0611x; 1.0611x over previous
//
#include <hip/hip_runtime.h>
#include <math.h>

// VGAE forward: 3x GCNConv + reparameterize.
// Pipeline: bucket-sort CSR build (bhist/bscan/bucket/fill2) -> MFMA GEMM1
//           (dis-scaled, f16 out) -> agg1(+b1,relu,f16) -> MFMA GEMM2
//           (W_mu|W_lv fused, dis-scaled, f16) -> agg2 (f32 + fused z).
// R2: hierarchical scan. R3: 16-bit intermediates, dis pre-scaled in GEMM.
// R4: scatter-free bucket-sort CSR build. R5: MFMA GEMM, W in VGPR B-frags.
// R6: k_bucket de-spilled (runtime-indexed my[16] -> scratch; now 2-pass over
//     L2-hot chunk, 4x per-wave LDS hist/cursors, EPB 2048). k_agg gathers
//     16B/lane (16 lanes/row, 4 edges/trip, unroll x2) + shfl_xor butterfly
//     reduce. k_final fused into k_agg<false> (z computed in-wave, NT stores).

#define SHIFT 9            // nodes per bucket = 512
#define EPB 2048           // edges per k_bucket block
#define HEPB 8192          // edges per k_bhist block
#define CAP 15104          // fill2 LDS srcs capacity (avg bucket = 8192)

using f32x4 = __attribute__((ext_vector_type(4))) float;
using f16x8 = __attribute__((ext_vector_type(8))) _Float16;
using f16x2 = __attribute__((ext_vector_type(2))) _Float16;

// Block-wide (256 thr) exclusive scan of one int per thread.
__device__ inline int scan256(int v, int* wsum) {
    __syncthreads();  // protect wsum reuse across calls
    int lane = threadIdx.x & 63, wid = threadIdx.x >> 6;
    int s = v;
#pragma unroll
    for (int d = 1; d < 64; d <<= 1) {
        int u = __shfl_up(s, d, 64);
        if (lane >= d) s += u;
    }
    if (lane == 63) wsum[wid] = s;
    __syncthreads();
    int off = 0;
    for (int w = 0; w < wid; w++) off += wsum[w];
    return off + s - v;
}

// Per-block LDS histogram of bucket ids -> global bucket histogram.
// 4x per-wave replication to cut LDS-atomic serialization.
__global__ __launch_bounds__(256) void k_bhist(const int* __restrict__ coli,
                                               int* __restrict__ gbh,
                                               int E, int NB) {
    __shared__ int lh[4][256];
    int t = threadIdx.x, w = t >> 6;
    lh[0][t] = 0; lh[1][t] = 0; lh[2][t] = 0; lh[3][t] = 0;
    __syncthreads();
    int base = blockIdx.x * HEPB;
    for (int i = t; i < HEPB; i += 256) {
        int e = base + i;
        if (e < E) atomicAdd(&lh[w][coli[e] >> SHIFT], 1);
    }
    __syncthreads();
    if (t < NB) {
        int v = lh[0][t] + lh[1][t] + lh[2][t] + lh[3][t];
        if (v) atomicAdd(&gbh[t], v);
    }
}

// One block: scan bucket sums -> bucketptr + cursors; rowptr[N]=E.
__global__ __launch_bounds__(256) void k_bscan(const int* __restrict__ gbh,
                                               int* __restrict__ bptr,
                                               int* __restrict__ bcur,
                                               int NB, int E,
                                               int* __restrict__ rowptr, int N) {
    __shared__ int wsum[4];
    int t = threadIdx.x;
    int v = (t < NB) ? gbh[t] : 0;
    int e = scan256(v, wsum);
    if (t < NB) { bptr[t] = e; bcur[t] = e; }
    if (t == 0) { bptr[NB] = E; rowptr[N] = E; }
}

// Bin EPB edges into LDS by bucket, burst-write (row,col) records to
// contiguous per-bucket runs. Two passes over the (L2-hot) chunk instead of
// a runtime-indexed register array (which spilled to scratch). Per-wave
// histograms + cursors (4x) cut LDS-atomic contention.
__global__ __launch_bounds__(256) void k_bucket(const int* __restrict__ rowi,
                                                const int* __restrict__ coli,
                                                int* __restrict__ bcur,
                                                int2* __restrict__ recs,
                                                int E, int NB) {
    __shared__ int lh[4][256], lcur[4][256], excl[256], gbase[256], wsum[4];
    __shared__ int2 stage[EPB];
    int t = threadIdx.x, w = t >> 6;
    lh[0][t] = 0; lh[1][t] = 0; lh[2][t] = 0; lh[3][t] = 0;
    __syncthreads();
    int base = blockIdx.x * EPB;
    int nE = min(EPB, E - base);
    // pass A: per-wave histogram
    for (int i = t; i < nE; i += 256)
        atomicAdd(&lh[w][coli[base + i] >> SHIFT], 1);
    __syncthreads();
    int h0 = lh[0][t], h1 = lh[1][t], h2 = lh[2][t], h3 = lh[3][t];
    int tot = h0 + h1 + h2 + h3;
    int ex = scan256(tot, wsum);
    excl[t] = ex;
    lcur[0][t] = ex;
    lcur[1][t] = ex + h0;
    lcur[2][t] = ex + h0 + h1;
    lcur[3][t] = ex + h0 + h1 + h2;
    if (t < NB && tot) gbase[t] = atomicAdd(&bcur[t], tot);
    __syncthreads();
    // pass B: re-read (L2-hot) and scatter into LDS stage, per-wave cursors
    for (int i = t; i < nE; i += 256) {
        int r = rowi[base + i], c = coli[base + i];
        int p = atomicAdd(&lcur[w][c >> SHIFT], 1);
        stage[p] = make_int2(r, c);
    }
    __syncthreads();
    // pass C: coalesced burst write per bucket run
    for (int i = t; i < nE; i += 256) {
        int2 r = stage[i];
        int bb = r.y >> SHIFT;
        recs[gbase[bb] + (i - excl[bb])] = r;
    }
}

// One block per bucket: local histogram -> rowptr/dis, LDS scatter of rows,
// coalesced burst write of srcs.
__global__ __launch_bounds__(256) void k_fill2(const int2* __restrict__ recs,
                                               const int* __restrict__ bptr,
                                               int* __restrict__ rowptr,
                                               float* __restrict__ dis,
                                               int* __restrict__ srcs, int N) {
    __shared__ int hist[512], excl[512], wsum[4];
    __shared__ int srcsL[CAP];
    int t = threadIdx.x;
    int b = blockIdx.x;
    int nbase = b << SHIFT;
    int start = bptr[b], end = bptr[b + 1];
    int cnt = end - start;
    hist[t] = 0;
    hist[t + 256] = 0;
    __syncthreads();
    for (int i = start + t; i < end; i += 256)
        atomicAdd(&hist[recs[i].y - nbase], 1);
    __syncthreads();
    int h0 = hist[2 * t], h1 = hist[2 * t + 1];
    int e0 = scan256(h0 + h1, wsum);
    excl[2 * t] = e0;
    excl[2 * t + 1] = e0 + h0;
    int n0 = nbase + 2 * t, n1 = nbase + 2 * t + 1;
    if (n0 < N) { rowptr[n0] = start + e0;      dis[n0] = rsqrtf((float)(h0 + 1)); }
    if (n1 < N) { rowptr[n1] = start + e0 + h0; dis[n1] = rsqrtf((float)(h1 + 1)); }
    __syncthreads();
    if (cnt <= CAP) {
        for (int i = start + t; i < end; i += 256) {
            int2 r = recs[i];
            int p = atomicAdd(&excl[r.y - nbase], 1);
            srcsL[p] = r.x;
        }
        __syncthreads();
        for (int i = t; i < cnt; i += 256) srcs[start + i] = srcsL[i];
    } else {  // pathological bucket: direct scatter (correct, slow)
        for (int i = start + t; i < end; i += 256) {
            int2 r = recs[i];
            int p = atomicAdd(&excl[r.y - nbase], 1);
            srcs[start + p] = r.x;
        }
    }
}

// Y[M,128] = dis[row] * (X[M,128] @ W[128,128]) -> f16, via MFMA 16x16x32.
// W cols [0,split) from Wa (f32, row stride split), [split,128) from Wb.
// W staged swizzled in LDS then hoisted into 32 f16x8 VGPR B-frags.
// Verified layouts (learn_hip m89/m120):
//   A[m=lane&15][k=quad*8+j], B[k=quad*8+j][n=lane&15],
//   C/D col=lane&15 row=quad*4+reg.
template <bool XF16>
__global__ __launch_bounds__(256) void k_gemm(const void* __restrict__ Xv,
                                              const float* __restrict__ Wa,
                                              const float* __restrict__ Wb,
                                              int split,
                                              const float* __restrict__ dis,
                                              _Float16* __restrict__ Y,
                                              int M, int ngroups) {
    __shared__ _Float16 Wl[16384];  // 32 KB swizzled
    int tid = threadIdx.x;
    int wbs = 128 - split;
    for (int i = tid; i < 16384; i += 256) {
        int k = i >> 7, n = i & 127;
        float v = (n < split) ? Wa[k * split + n] : Wb[k * wbs + (n - split)];
        int tt = n >> 4, c = (k >> 5), q = (k >> 3) & 3, ln = q * 16 + (n & 15);
        Wl[(((tt * 4 + c) * 64) + ln) * 8 + (k & 7)] = (_Float16)v;
    }
    __syncthreads();

    int lane = tid & 63, w = tid >> 6;
    f16x8 B[32];
#pragma unroll
    for (int i = 0; i < 32; i++)
        B[i] = *(const f16x8*)&Wl[(i * 64 + lane) * 8];

    int m16 = lane & 15, quad = lane >> 4;
    for (int g = blockIdx.x; g < ngroups; g += gridDim.x) {
        int rowbase = g * 64 + w * 16;
        if (rowbase >= M) continue;
        int arow = min(rowbase + m16, M - 1);
        f16x8 A[4];
        if (XF16) {
            const _Float16* X = (const _Float16*)Xv;
#pragma unroll
            for (int c = 0; c < 4; c++)
                A[c] = *(const f16x8*)&X[arow * 128 + c * 32 + quad * 8];
        } else {
            const float* X = (const float*)Xv;
#pragma unroll
            for (int c = 0; c < 4; c++) {
                float4 u0 = *(const float4*)&X[arow * 128 + c * 32 + quad * 8];
                float4 u1 = *(const float4*)&X[arow * 128 + c * 32 + quad * 8 + 4];
                f16x8 a;
                a[0] = (_Float16)u0.x; a[1] = (_Float16)u0.y;
                a[2] = (_Float16)u0.z; a[3] = (_Float16)u0.w;
                a[4] = (_Float16)u1.x; a[5] = (_Float16)u1.y;
                a[6] = (_Float16)u1.z; a[7] = (_Float16)u1.w;
                A[c] = a;
            }
        }

        f32x4 acc[8];
#pragma unroll
        for (int t = 0; t < 8; t++) acc[t] = (f32x4)(0.f);
#pragma unroll
        for (int t = 0; t < 8; t++)
#pragma unroll
            for (int c = 0; c < 4; c++)
                acc[t] = __builtin_amdgcn_mfma_f32_16x16x32_f16(
                    A[c], B[t * 4 + c], acc[t], 0, 0, 0);

#pragma unroll
        for (int r = 0; r < 4; r++) {
            int row = rowbase + quad * 4 + r;
            if (row < M) {
                float d = dis[row];
#pragma unroll
                for (int t = 0; t < 8; t++)
                    Y[row * 128 + t * 16 + m16] = (_Float16)(d * acc[t][r]);
            }
        }
    }
}

// F is dis-prescaled f16 [N,128]. out[i] = bias + dis_i * (F[i] + sum F[src]).
// One wave per node; 16 lanes x f16x8 (16B) cover a row; the wave's 4
// lane-groups process 4 edges per trip (1KB/VMEM), unrolled x2 (2KB in
// flight). Group partials combined by shfl_xor butterfly (16,32).
// OF16: output f16 [N,128] with relu (layer 1).
// else: mu->outA, lv->outB (f32 [N,64] each) + fused z = mu+eps*exp(.5*lv).
template <bool OF16>
__global__ __launch_bounds__(256) void k_agg(const _Float16* __restrict__ F,
                                             const float* __restrict__ dis,
                                             const int* __restrict__ rowptr,
                                             const int* __restrict__ srcs,
                                             const float* __restrict__ ba,
                                             const float* __restrict__ bb,
                                             void* __restrict__ outA,
                                             void* __restrict__ outB,
                                             const float* __restrict__ eps,
                                             float* __restrict__ z, int N) {
    int node = blockIdx.x * 4 + (threadIdx.x >> 6);
    if (node >= N) return;
    int lane = threadIdx.x & 63;
    int g = lane >> 4, sl = lane & 15;
    const f16x8* Fr = (const f16x8*)F;   // row r chunk c at Fr[r*16 + c]

    float acc[8];
#pragma unroll
    for (int j = 0; j < 8; j++) acc[j] = 0.f;
    if (g == 0) {  // self term (F already dis-prescaled)
        f16x8 v = Fr[node * 16 + sl];
#pragma unroll
        for (int j = 0; j < 8; j++) acc[j] = (float)v[j];
    }

    int s = rowptr[node], e = rowptr[node + 1];
    int t = s;
    for (; t + 8 <= e; t += 8) {
        int i0 = srcs[t + g];
        int i1 = srcs[t + 4 + g];
        f16x8 v0 = Fr[i0 * 16 + sl];
        f16x8 v1 = Fr[i1 * 16 + sl];
#pragma unroll
        for (int j = 0; j < 8; j++)
            acc[j] += (float)v0[j] + (float)v1[j];
    }
    if (t + 4 <= e) {
        int i0 = srcs[t + g];
        f16x8 v0 = Fr[i0 * 16 + sl];
#pragma unroll
        for (int j = 0; j < 8; j++) acc[j] += (float)v0[j];
        t += 4;
    }
    if (t < e) {  // masked tail: 1..3 edges
        int idx = t + g;
        bool ok = idx < e;
        int i0 = ok ? srcs[idx] : 0;
        f16x8 v0 = Fr[i0 * 16 + sl];
        if (ok) {
#pragma unroll
            for (int j = 0; j < 8; j++) acc[j] += (float)v0[j];
        }
    }

    // butterfly reduce over the 4 lane-groups (all lanes end with full sum)
#pragma unroll
    for (int j = 0; j < 8; j++) {
        acc[j] += __shfl_xor(acc[j], 16);
        acc[j] += __shfl_xor(acc[j], 32);
    }

    float di = dis[node];
    if constexpr (OF16) {
        float4 b0 = *(const float4*)&ba[sl * 8];
        float4 b1 = *(const float4*)&ba[sl * 8 + 4];
        if (lane < 16) {
            f16x8 o;
            o[0] = (_Float16)fmaxf(fmaf(di, acc[0], b0.x), 0.f);
            o[1] = (_Float16)fmaxf(fmaf(di, acc[1], b0.y), 0.f);
            o[2] = (_Float16)fmaxf(fmaf(di, acc[2], b0.z), 0.f);
            o[3] = (_Float16)fmaxf(fmaf(di, acc[3], b0.w), 0.f);
            o[4] = (_Float16)fmaxf(fmaf(di, acc[4], b1.x), 0.f);
            o[5] = (_Float16)fmaxf(fmaf(di, acc[5], b1.y), 0.f);
            o[6] = (_Float16)fmaxf(fmaf(di, acc[6], b1.z), 0.f);
            o[7] = (_Float16)fmaxf(fmaf(di, acc[7], b1.w), 0.f);
            ((f16x8*)outA)[node * 16 + sl] = o;
        }
    } else {
        // lanes (sl<8): mu cols sl*8..+7 ; lanes (sl>=8): lv cols (sl-8)*8..+7
        const float* bp = (sl < 8) ? ba : bb;
        int cb = (sl & 7) * 8;
        float4 b0 = *(const float4*)&bp[cb];
        float4 b1 = *(const float4*)&bp[cb + 4];
        float o[8];
        o[0] = fmaf(di, acc[0], b0.x);
        o[1] = fmaf(di, acc[1], b0.y);
        o[2] = fmaf(di, acc[2], b0.z);
        o[3] = fmaf(di, acc[3], b0.w);
        o[4] = fmaf(di, acc[4], b1.x);
        o[5] = fmaf(di, acc[5], b1.y);
        o[6] = fmaf(di, acc[6], b1.z);
        o[7] = fmaf(di, acc[7], b1.w);
        if (lane < 16) {
            float* op = (sl < 8) ? (float*)outA : (float*)outB;
            f32x4 s0, s1;
            s0[0] = o[0]; s0[1] = o[1]; s0[2] = o[2]; s0[3] = o[3];
            s1[0] = o[4]; s1[1] = o[5]; s1[2] = o[6]; s1[3] = o[7];
            __builtin_nontemporal_store(s0, (f32x4*)&op[node * 64 + cb]);
            __builtin_nontemporal_store(s1, (f32x4*)&op[node * 64 + cb + 4]);
        }
        // fused reparameterize: lane l (<8) pulls lv chunk from lane l+8
        float lvv[8];
#pragma unroll
        for (int j = 0; j < 8; j++) lvv[j] = __shfl_xor(o[j], 8);
        if (lane < 8) {
            int zb = node * 64 + sl * 8;
            float4 e0 = *(const float4*)&eps[zb];
            float4 e1 = *(const float4*)&eps[zb + 4];
            f32x4 z0, z1;
            z0[0] = fmaf(e0.x, expf(0.5f * lvv[0]), o[0]);
            z0[1] = fmaf(e0.y, expf(0.5f * lvv[1]), o[1]);
            z0[2] = fmaf(e0.z, expf(0.5f * lvv[2]), o[2]);
            z0[3] = fmaf(e0.w, expf(0.5f * lvv[3]), o[3]);
            z1[0] = fmaf(e1.x, expf(0.5f * lvv[4]), o[4]);
            z1[1] = fmaf(e1.y, expf(0.5f * lvv[5]), o[5]);
            z1[2] = fmaf(e1.z, expf(0.5f * lvv[6]), o[6]);
            z1[3] = fmaf(e1.w, expf(0.5f * lvv[7]), o[7]);
            __builtin_nontemporal_store(z0, (f32x4*)&z[zb]);
            __builtin_nontemporal_store(z1, (f32x4*)&z[zb + 4]);
        }
    }
}

extern "C" void kernel_launch(void* const* d_in, const int* in_sizes, int n_in,
                              void* d_out, int out_size, void* d_ws, size_t ws_size,
                              hipStream_t stream) {
    const float* x   = (const float*)d_in[0];
    const int*   ei  = (const int*)d_in[1];
    const float* W1  = (const float*)d_in[2];
    const float* b1  = (const float*)d_in[3];
    const float* Wmu = (const float*)d_in[4];
    const float* bmu = (const float*)d_in[5];
    const float* Wlv = (const float*)d_in[6];
    const float* blv = (const float*)d_in[7];
    const float* eps = (const float*)d_in[8];

    int N = in_sizes[0] / 128;   // 100000
    int E = in_sizes[1] / 2;     // 1600000
    const int* rowi = ei;        // edge_index[0]
    const int* coli = ei + E;    // edge_index[1]
    int NB = (N + (1 << SHIFT) - 1) >> SHIFT;   // 196 buckets

    char* ws = (char*)d_ws;
    size_t off = 0;
    auto alloc = [&](size_t bytes) -> void* {
        void* p = ws + off;
        off += (bytes + 255) & ~(size_t)255;
        return p;
    };
    _Float16* bufA = (_Float16*)alloc((size_t)N * 128 * 2);  // F'1, F'2
    _Float16* bufB = (_Float16*)alloc((size_t)N * 128 * 2);  // h (f16)
    float* dis    = (float*)alloc((size_t)N * 4);
    int*   rowptr = (int*)alloc((size_t)(N + 1) * 4);
    int*   srcs   = (int*)alloc((size_t)E * 4);
    int2*  recs   = (int2*)alloc((size_t)E * 8);
    int*   bhist  = (int*)alloc((size_t)NB * 4);
    int*   bptr   = (int*)alloc((size_t)(NB + 1) * 4);
    int*   bcur   = (int*)alloc((size_t)NB * 4);

    float* zo  = (float*)d_out;                 // [N,64]
    float* muo = zo + (size_t)N * 64;           // [N,64]
    float* lvo = zo + (size_t)N * 128;          // [N,64]

    hipMemsetAsync(bhist, 0, (size_t)NB * 4, stream);
    k_bhist<<<(E + HEPB - 1) / HEPB, 256, 0, stream>>>(coli, bhist, E, NB);
    k_bscan<<<1, 256, 0, stream>>>(bhist, bptr, bcur, NB, E, rowptr, N);
    k_bucket<<<(E + EPB - 1) / EPB, 256, 0, stream>>>(rowi, coli, bcur, recs, E, NB);
    k_fill2<<<NB, 256, 0, stream>>>(recs, bptr, rowptr, dis, srcs, N);

    int ngroups = (N + 63) / 64;
    int gblk = ngroups < 640 ? ngroups : 640;
    // F'1 = dis . (x @ W1)   (f16, MFMA)
    k_gemm<false><<<gblk, 256, 0, stream>>>(x, W1, W1, 128, dis, bufA, N, ngroups);
    // h = relu(dis . (F'1[i] + sum F'1[src]) + b1)   (f16)
    k_agg<true><<<(N + 3) / 4, 256, 0, stream>>>(bufA, dis, rowptr, srcs,
                                                 b1, b1, bufB, bufB,
                                                 nullptr, nullptr, N);
    // F'2 = dis . (h @ [Wmu|Wlv])   (f16, MFMA)
    k_gemm<true><<<gblk, 256, 0, stream>>>(bufB, Wmu, Wlv, 64, dis, bufA, N, ngroups);
    // mu/lv = dis . (F'2[i] + sum F'2[src]) + b ; z fused in-wave
    k_agg<false><<<(N + 3) / 4, 256, 0, stream>>>(bufA, dis, rowptr, srcs,
                                                  bmu, blv, muo, lvo,
                                                  eps, zo, N);
}